// Round 5
// baseline (604.608 us; speedup 1.0000x reference)
//
#include <hip/hip_runtime.h>
#include <hip/hip_bf16.h>
#include <hip/hip_cooperative_groups.h>

namespace cg = cooperative_groups;

// Problem constants
#define NND 50000      // nodes
#define NED 800000     // edges (without self-loops)
#define INC 10
#define HID 96
#define OUTC 48
#define NOUT (NND*OUTC)
#define MTILES 3125    // 50000 / 16
#define NW 98          // dest windows of SPAN nodes
#define SPAN 512
#define EW_CAP 9216    // CSR capacity per window (Poisson 8163 + 11 sigma)
#define PB 200         // partition blocks
#define PBE 4000       // edges per partition block (200*4000 = 800000 exact)
#define GRID 256       // cooperative grid (1 block/CU, co-resident)

typedef __hip_bfloat16 bf16;
typedef __attribute__((ext_vector_type(8))) short short8;
typedef __attribute__((ext_vector_type(4))) float f32x4;

// ---- workspace layout ----
// 256B header reserved (unused now). F floats (from d_ws+256):
#define W1F_O  0L                 // 960 (W1 then b1: 1056 contiguous)
#define B1F_O  960L               // 96
#define BMF_O  1056L              // 48
#define BLF_O  1104L              // 48
#define DIS_O  1152L              // 50000 rsqrt(deg+1)
#define XS_O   51152L             // 500000 x' = dis*x (fp32)
#define FLOATS_TOT 551152L
// then: h' [NND*96] bf16, wct [96*96] bf16
// then ints: cnt[50000], start[50000], part[800000], smat[NW*PB], cmat[NW*PB];
// then csr u16 [NW*EW_CAP]

__device__ __forceinline__ float b2f(bf16 v) { return __bfloat162float(v); }
__device__ __forceinline__ float bfLo(unsigned int p) { return __uint_as_float(p << 16); }
__device__ __forceinline__ float bfHi(unsigned int p) { return __uint_as_float(p & 0xffff0000u); }
__device__ __forceinline__ unsigned short f2bu(float v) {
    return __bfloat16_as_ushort(__float2bfloat16(v));
}

// unpack-accumulate one 192B h'-row third-chunk triple into the 24-float acc
#define ACCADD(Q0, Q1, Q2) do {                                             \
    const uint4 q0 = (Q0), q1 = (Q1), q2 = (Q2);                            \
    acc[0][0] += bfLo(q0.x); acc[0][1] += bfHi(q0.x);                       \
    acc[0][2] += bfLo(q0.y); acc[0][3] += bfHi(q0.y);                       \
    acc[0][4] += bfLo(q0.z); acc[0][5] += bfHi(q0.z);                       \
    acc[0][6] += bfLo(q0.w); acc[0][7] += bfHi(q0.w);                       \
    acc[1][0] += bfLo(q1.x); acc[1][1] += bfHi(q1.x);                       \
    acc[1][2] += bfLo(q1.y); acc[1][3] += bfHi(q1.y);                       \
    acc[1][4] += bfLo(q1.z); acc[1][5] += bfHi(q1.z);                       \
    acc[1][6] += bfLo(q1.w); acc[1][7] += bfHi(q1.w);                       \
    acc[2][0] += bfLo(q2.x); acc[2][1] += bfHi(q2.x);                       \
    acc[2][2] += bfLo(q2.y); acc[2][3] += bfHi(q2.y);                       \
    acc[2][4] += bfLo(q2.z); acc[2][5] += bfHi(q2.z);                       \
    acc[2][6] += bfLo(q2.w); acc[2][7] += bfHi(q2.w);                       \
} while (0)

// LDS: one union reused across the 4 phases (max = phase D, 48 KB)
union SU {
    struct { int counts[NW]; int cur[NW]; unsigned int buf[PBE]; } a;           // 16.8 KB
    struct { int Lrun[PB]; int Srun[PB]; int hist[SPAN]; int cur[SPAN];
             float dl[SPAN]; int wsum[8]; } b;                                   // 7.8 KB
    struct { float w1s[1056]; } c;                                               // 4.2 KB
    struct { float4 red[8][64][6]; } d;                                          // 48 KB
};

// Single cooperative kernel: partition -> grid.sync -> window/CSR build ->
// grid.sync -> layer1 -> grid.sync -> gather+MFMA heads. Phase bodies are the
// verified 4-kernel bodies. 256 blocks x 1024 thr.
// NOTE: no min-waves arg in launch_bounds — a 1024-thread block already
// implies 4 waves/EU (VGPR cap 128); the previous ",4" drove allocation to
// 64 VGPR and spilled phase D's ~90 live regs to scratch (R4: +90MB fetch,
// +90MB write, 510us).
__global__ __launch_bounds__(1024) void k_all(
        const int* ei, const void* x,
        const void* w1, const void* b1, const void* wm, const void* bm,
        const void* wl, const void* bl,
        float* F, unsigned short* wct, unsigned int* part, int* smat, int* cmat,
        int* cnt, int* start, unsigned short* csr, unsigned short* h, void* dout) {
    cg::grid_group grid = cg::this_grid();
    __shared__ SU u;
    __shared__ int s_oddnz, s_big;
    const int tid = threadIdx.x, bid = blockIdx.x;
    const int wave = tid >> 6, lane = tid & 63;

    // ---- dtype sniff (every block; ~5 KB L2-broadcast reads) ----
    if (tid == 0) { s_oddnz = 0; s_big = 0; }
    if (tid < NW) u.a.counts[tid] = 0;
    __syncthreads();
    if (tid < 128) {
        if (ei[2 * tid + 1] != 0) atomicOr(&s_oddnz, 1);
    }
    if (tid < 256) {
        const unsigned short* xs = (const unsigned short*)x;
        unsigned short uu = xs[tid * 8];
        float f = __uint_as_float(((unsigned int)uu) << 16);
        int big = !(fabsf(f) < 64.0f);
        unsigned short u2 = xs[tid * 8 + 5];
        float f2 = __uint_as_float(((unsigned int)u2) << 16);
        big |= !(fabsf(f2) < 64.0f);
        if (big) atomicOr(&s_big, 1);
    }
    __syncthreads();
    const int iw = (s_oddnz == 0) ? 1 : 0;   // 1 = int64 edge_index
    const int ff = s_big ? 1 : 0;            // 1 = fp32 floats

    // ======== Phase A: partition + weight conversion ========
    if (bid < 11) {   // weights: 11*1024 = 11264 >= 10368
        int idx = bid * 1024 + tid;
        if (idx < 10368) {
            const void* src; long off; int mode; long dst = 0;
            if      (idx < 960)  { src = w1; off = idx;        mode = 0; dst = W1F_O + idx; }
            else if (idx < 1056) { src = b1; off = idx - 960;  mode = 0; dst = B1F_O + (idx - 960); }
            else if (idx < 1104) { src = bm; off = idx - 1056; mode = 0; dst = BMF_O + (idx - 1056); }
            else if (idx < 1152) { src = bl; off = idx - 1104; mode = 0; dst = BLF_O + (idx - 1104); }
            else if (idx < 5760) { src = wm; off = idx - 1152; mode = 1; }
            else                 { src = wl; off = idx - 5760; mode = 2; }
            float v = ff ? ((const float*)src)[off] : b2f(((const bf16*)src)[off]);
            if (mode == 0) F[dst] = v;
            else if (mode == 1) wct[(off % OUTC) * (long)HID + off / OUTC] = f2bu(v);
            else                wct[(OUTC + off % OUTC) * (long)HID + off / OUTC] = f2bu(v);
        }
    }
    if (bid < PB) {
        unsigned int wreg[4];
        int base = bid * 1000;              // groups of 4 edges
        int j = tid;
        if (j < 1000) {
            int j4 = base + j;
            int r0, r1, r2, r3, c0, c1, c2, c3;
            if (iw) {
                const int4* pr = (const int4*)ei;
                const int4* pc = (const int4*)(ei + 2L * NED);
                int4 ra = pr[2 * j4], rb = pr[2 * j4 + 1];
                int4 ca = pc[2 * j4], cb = pc[2 * j4 + 1];
                r0 = ra.x; r1 = ra.z; r2 = rb.x; r3 = rb.z;
                c0 = ca.x; c1 = ca.z; c2 = cb.x; c3 = cb.z;
            } else {
                int4 ra = ((const int4*)ei)[j4];
                int4 ca = ((const int4*)(ei + NED))[j4];
                r0 = ra.x; r1 = ra.y; r2 = ra.z; r3 = ra.w;
                c0 = ca.x; c1 = ca.y; c2 = ca.z; c3 = ca.w;
            }
            wreg[0] = (unsigned)r0 | ((unsigned)c0 << 16);
            wreg[1] = (unsigned)r1 | ((unsigned)c1 << 16);
            wreg[2] = (unsigned)r2 | ((unsigned)c2 << 16);
            wreg[3] = (unsigned)r3 | ((unsigned)c3 << 16);
            atomicAdd(&u.a.counts[wreg[0] >> 25], 1);
            atomicAdd(&u.a.counts[wreg[1] >> 25], 1);
            atomicAdd(&u.a.counts[wreg[2] >> 25], 1);
            atomicAdd(&u.a.counts[wreg[3] >> 25], 1);
        }
        __syncthreads();
        if (tid < NW) {   // tiny serial exclusive scan per thread
            int run = 0;
            for (int jj = 0; jj < tid; ++jj) run += u.a.counts[jj];
            u.a.cur[tid] = run;
            cmat[tid * PB + bid] = u.a.counts[tid];
            smat[tid * PB + bid] = bid * PBE + run;
        }
        __syncthreads();
        if (j < 1000) {
#pragma unroll
            for (int q = 0; q < 4; ++q) {
                unsigned int w = wreg[q];
                int pos = atomicAdd(&u.a.cur[w >> 25], 1);
                u.a.buf[pos] = w;
            }
        }
        __syncthreads();
        for (int i = tid; i < PBE; i += 1024) part[bid * PBE + i] = u.a.buf[i];
    }
    __threadfence();
    grid.sync();

    // ======== Phase B: window build (blocks 0..97) ========
    if (bid < NW) {
        const int w = bid;
        if (tid < PB) { u.b.Lrun[tid] = cmat[w * PB + tid]; u.b.Srun[tid] = smat[w * PB + tid]; }
        if (tid < SPAN) u.b.hist[tid] = 0;
        __syncthreads();
        unsigned int lo = (unsigned)w * SPAN;
        for (int rb = wave; rb < PB; rb += 16) {
            int L = u.b.Lrun[rb], S = u.b.Srun[rb];
            for (int i = lane; i < L; i += 64)
                atomicAdd(&u.b.hist[(part[S + i] >> 16) - lo], 1);
        }
        __syncthreads();
        // inclusive scan: in-wave shuffle + 8-wide cross-wave
        int v = 0;
        if (tid < SPAN) {
            v = u.b.hist[tid];
#pragma unroll
            for (int d = 1; d < 64; d <<= 1) {
                int t = __shfl_up(v, d, 64);
                if (lane >= d) v += t;
            }
            if (lane == 63) u.b.wsum[wave] = v;
        }
        __syncthreads();
        if (tid < 8) {
            int sv = u.b.wsum[tid];
#pragma unroll
            for (int d = 1; d < 8; d <<= 1) {
                int t = __shfl_up(sv, d, 64);
                if (tid >= d) sv += t;
            }
            u.b.wsum[tid] = sv;
        }
        __syncthreads();
        if (tid < SPAN) {
            int stv = v + (wave ? u.b.wsum[wave - 1] : 0);
            int h0 = u.b.hist[tid];
            int abs0 = w * EW_CAP + (stv - h0);
            u.b.cur[tid] = abs0;
            float dis = rsqrtf((float)h0 + 1.0f);
            u.b.dl[tid] = dis;
            int g = (int)lo + tid;
            if (g < NND) {
                cnt[g] = h0; start[g] = abs0;
                F[DIS_O + g] = dis;
            }
        }
        __syncthreads();
        // x' = dis * x from raw input (coalesced)
        for (int i = tid; i < SPAN * INC; i += 1024) {
            int node = (int)lo + i / INC;
            if (node < NND) {
                long xo = (long)node * INC + (i % INC);
                float xv = ff ? ((const float*)x)[xo] : b2f(((const bf16*)x)[xo]);
                F[XS_O + xo] = u.b.dl[i / INC] * xv;
            }
        }
        int lim = (w + 1) * EW_CAP;
        for (int rb = wave; rb < PB; rb += 16) {
            int L = u.b.Lrun[rb], S = u.b.Srun[rb];
            for (int i = lane; i < L; i += 64) {
                unsigned int e = part[S + i];
                int pos = atomicAdd(&u.b.cur[(e >> 16) - lo], 1);
                if (pos < lim) csr[pos] = (unsigned short)(e & 0xffffu);
            }
        }
    }
    __threadfence();
    grid.sync();

    // ======== Phase C: layer1 (grid-stride, 8 threads/node) ========
    for (int i = tid; i < 1056; i += 1024) u.c.w1s[i] = F[W1F_O + i];
    __syncthreads();
    for (int idx = bid * 1024 + tid; idx < NND * 8; idx += GRID * 1024) {
        int node = idx >> 3, sub = idx & 7;
        int s = start[node], t = s + cnt[node];
        int lim = ((node >> 9) + 1) * EW_CAP;
        if (t > lim) t = lim;                 // capacity guard
        float ax[INC];
#pragma unroll
        for (int j = 0; j < INC; ++j) ax[j] = 0.0f;
        int k = s + sub;
        for (; k + 8 < t; k += 16) {          // 2 records: k and k+8
            int s0 = csr[k], s1 = csr[k + 8];
            const float2* x0 = (const float2*)(F + XS_O + (long)s0 * INC);
            const float2* x1 = (const float2*)(F + XS_O + (long)s1 * INC);
            float2 a0 = x0[0], a1 = x0[1], a2 = x0[2], a3 = x0[3], a4 = x0[4];
            float2 b0 = x1[0], b1 = x1[1], b2 = x1[2], b3 = x1[3], b4 = x1[4];
            ax[0] += a0.x + b0.x; ax[1] += a0.y + b0.y;
            ax[2] += a1.x + b1.x; ax[3] += a1.y + b1.y;
            ax[4] += a2.x + b2.x; ax[5] += a2.y + b2.y;
            ax[6] += a3.x + b3.x; ax[7] += a3.y + b3.y;
            ax[8] += a4.x + b4.x; ax[9] += a4.y + b4.y;
        }
        if (k < t) {                           // tail: at most one record
            int s0 = csr[k];
            const float2* x0 = (const float2*)(F + XS_O + (long)s0 * INC);
#pragma unroll
            for (int j = 0; j < 5; ++j) {
                float2 v = x0[j];
                ax[2 * j]     += v.x;
                ax[2 * j + 1] += v.y;
            }
        }
        if (sub == 0) {   // self term: + x'_c
            const float2* xr = (const float2*)(F + XS_O + (long)node * INC);
#pragma unroll
            for (int j = 0; j < 5; ++j) {
                float2 v = xr[j];
                ax[2 * j]     += v.x;
                ax[2 * j + 1] += v.y;
            }
        }
        // octet butterfly (whole octets active together; masks stay in-octet)
#pragma unroll
        for (int j = 0; j < INC; ++j) {
            ax[j] += __shfl_xor(ax[j], 1, 64);
            ax[j] += __shfl_xor(ax[j], 2, 64);
            ax[j] += __shfl_xor(ax[j], 4, 64);
        }
        float dn = F[DIS_O + node];
#pragma unroll
        for (int j = 0; j < INC; ++j) ax[j] *= dn;
        int f0 = sub * 12;
        unsigned int* hrow = (unsigned int*)(h + (size_t)node * HID);
#pragma unroll
        for (int f = f0; f < f0 + 12; f += 2) {
            float a0 = u.c.w1s[960 + f], a1 = u.c.w1s[960 + f + 1];
#pragma unroll
            for (int kk = 0; kk < INC; ++kk) {
                a0 = fmaf(ax[kk], u.c.w1s[kk * HID + f], a0);
                a1 = fmaf(ax[kk], u.c.w1s[kk * HID + f + 1], a1);
            }
            a0 = fmaxf(a0, 0.0f) * dn;     // h' = dis_c * relu(...)
            a1 = fmaxf(a1, 0.0f) * dn;
            unsigned int u0 = f2bu(a0), u1 = f2bu(a1);
            hrow[f >> 1] = u0 | (u1 << 16);
        }
    }
    __threadfence();
    grid.sync();

    // ======== Phase D: gather + MFMA heads ========
    // 16 waves = 8 tile-slots x 2 halves; tiles stride GRID*8 = 2048; 2 passes.
    {
        const int slot = wave >> 1, half = wave & 1;
        const int l16 = lane & 15, quad = lane >> 4;
        const uint4* hb4 = (const uint4*)h;   // h row = 12 uint4 (192 B)
#pragma unroll 1
        for (int p = 0; p < 2; ++p) {
            int mtile = p * (GRID * 8) + bid * 8 + slot;
            bool act = mtile < MTILES;
            int node = 0, s = 0, c = 0;
            float acc[3][8];
#pragma unroll
            for (int g = 0; g < 3; ++g)
#pragma unroll
                for (int j = 0; j < 8; ++j) acc[g][j] = 0.0f;
            if (act) {
                node = mtile * 16 + l16;
                long rowq = (long)node * 12;
                s = start[node]; c = cnt[node];
                int lim = ((node >> 9) + 1) * EW_CAP;
                if (s + c > lim) c = lim - s;
                if (half == 0) {   // self term
                    ACCADD(hb4[rowq + quad], hb4[rowq + 4 + quad], hb4[rowq + 8 + quad]);
                }
                int k = half;
                for (; k + 6 < c; k += 8) {
                    int e0 = csr[s + k], e1 = csr[s + k + 2], e2 = csr[s + k + 4], e3 = csr[s + k + 6];
                    long r0 = (long)e0 * 12, r1 = (long)e1 * 12, r2 = (long)e2 * 12, r3 = (long)e3 * 12;
                    uint4 x00 = hb4[r0 + quad], x01 = hb4[r0 + 4 + quad], x02 = hb4[r0 + 8 + quad];
                    uint4 x10 = hb4[r1 + quad], x11 = hb4[r1 + 4 + quad], x12 = hb4[r1 + 8 + quad];
                    uint4 x20 = hb4[r2 + quad], x21 = hb4[r2 + 4 + quad], x22 = hb4[r2 + 8 + quad];
                    uint4 x30 = hb4[r3 + quad], x31 = hb4[r3 + 4 + quad], x32 = hb4[r3 + 8 + quad];
                    ACCADD(x00, x01, x02);
                    ACCADD(x10, x11, x12);
                    ACCADD(x20, x21, x22);
                    ACCADD(x30, x31, x32);
                }
                for (; k < c; k += 2) {
                    int e0 = csr[s + k];
                    long r0 = (long)e0 * 12;
                    ACCADD(hb4[r0 + quad], hb4[r0 + 4 + quad], hb4[r0 + 8 + quad]);
                }
            }
            if (act && half == 1) {
#pragma unroll
                for (int g = 0; g < 3; ++g) {
                    u.d.red[slot][lane][2 * g]     = make_float4(acc[g][0], acc[g][1], acc[g][2], acc[g][3]);
                    u.d.red[slot][lane][2 * g + 1] = make_float4(acc[g][4], acc[g][5], acc[g][6], acc[g][7]);
                }
            }
            __syncthreads();
            if (act && half == 0) {
#pragma unroll
                for (int g = 0; g < 3; ++g) {
                    float4 uu = u.d.red[slot][lane][2 * g], vv = u.d.red[slot][lane][2 * g + 1];
                    acc[g][0] += uu.x; acc[g][1] += uu.y; acc[g][2] += uu.z; acc[g][3] += uu.w;
                    acc[g][4] += vv.x; acc[g][5] += vv.y; acc[g][6] += vv.z; acc[g][7] += vv.w;
                }
                float dn = F[DIS_O + node];
                short8 af[3];
#pragma unroll
                for (int g = 0; g < 3; ++g)
#pragma unroll
                    for (int j = 0; j < 8; ++j)
                        af[g][j] = (short)f2bu(acc[g][j] * dn);
#pragma unroll
                for (int nt = 0; nt < 6; ++nt) {
                    const unsigned short* wb = wct + ((size_t)nt * 16 + l16) * HID + quad * 8;
                    short8 b0 = *(const short8*)(wb);
                    short8 b1 = *(const short8*)(wb + 32);
                    short8 b2 = *(const short8*)(wb + 64);
                    f32x4 cacc = {0.0f, 0.0f, 0.0f, 0.0f};
                    cacc = __builtin_amdgcn_mfma_f32_16x16x32_bf16(af[0], b0, cacc, 0, 0, 0);
                    cacc = __builtin_amdgcn_mfma_f32_16x16x32_bf16(af[1], b1, cacc, 0, 0, 0);
                    cacc = __builtin_amdgcn_mfma_f32_16x16x32_bf16(af[2], b2, cacc, 0, 0, 0);
                    int n = nt * 16 + l16;                 // 0..95: <48 mu, >=48 logstd
                    float bias = (n < OUTC) ? F[BMF_O + n] : F[BLF_O + n - OUTC];
                    long obase = (n < OUTC) ? ((long)n) : (NOUT + (long)(n - OUTC));
#pragma unroll
                    for (int r = 0; r < 4; ++r) {
                        int m = mtile * 16 + quad * 4 + r;
                        float val = cacc[r] + bias;
                        long oi = (long)m * OUTC + obase;
                        if (ff) ((float*)dout)[oi] = val;
                        else    ((bf16*)dout)[oi] = __float2bfloat16(val);
                    }
                }
            }
            __syncthreads();   // red reuse safety for next pass
        }
    }
}

extern "C" void kernel_launch(void* const* d_in, const int* in_sizes, int n_in,
                              void* d_out, int out_size, void* d_ws, size_t ws_size,
                              hipStream_t stream) {
    const int* ei = (const int*)d_in[1];
    const void* x = d_in[0];
    const void* w1 = d_in[2]; const void* b1 = d_in[3];
    const void* wm = d_in[4]; const void* bm = d_in[5];
    const void* wl = d_in[6]; const void* bl = d_in[7];
    float* F = (float*)((char*)d_ws + 256);
    unsigned short* h   = (unsigned short*)(F + FLOATS_TOT);
    unsigned short* wct = h + (size_t)NND * HID;
    int* cnt   = (int*)(wct + (size_t)HID * HID);
    int* start = cnt + NND;
    unsigned int* part = (unsigned int*)(start + NND);
    int* smat = (int*)(part + NED);
    int* cmat = smat + NW * PB;
    unsigned short* csr = (unsigned short*)(cmat + NW * PB);

    void* args[] = {
        (void*)&ei, (void*)&x, (void*)&w1, (void*)&b1, (void*)&wm, (void*)&bm,
        (void*)&wl, (void*)&bl, (void*)&F, (void*)&wct, (void*)&part,
        (void*)&smat, (void*)&cmat, (void*)&cnt, (void*)&start, (void*)&csr,
        (void*)&h, (void*)&d_out
    };
    hipLaunchCooperativeKernel((void*)k_all, dim3(GRID), dim3(1024), args, 0, stream);
}

// Round 6
// 589.404 us; speedup vs baseline: 1.0258x; 1.0258x over previous
//
#include <hip/hip_runtime.h>
#include <hip/hip_bf16.h>
#include <hip/hip_cooperative_groups.h>

namespace cg = cooperative_groups;

// Problem constants
#define NND 50000      // nodes
#define NED 800000     // edges (without self-loops)
#define INC 10
#define HID 96
#define OUTC 48
#define NOUT (NND*OUTC)
#define MTILES 3125    // 50000 / 16
#define NW 98          // dest windows of SPAN nodes
#define SPAN 512
#define EW_CAP 9216    // CSR capacity per window (Poisson 8163 + 11 sigma)
#define PB 200         // partition blocks
#define PBE 4000       // edges per partition block (200*4000 = 800000 exact)
#define GRID 256       // cooperative grid (1 block/CU, co-resident)

typedef __hip_bfloat16 bf16;
typedef __attribute__((ext_vector_type(8))) short short8;
typedef __attribute__((ext_vector_type(4))) float f32x4;

// ---- workspace layout ----
// 256B header reserved (unused now). F floats (from d_ws+256):
#define W1F_O  0L                 // 960 (W1 then b1: 1056 contiguous)
#define B1F_O  960L               // 96
#define BMF_O  1056L              // 48
#define BLF_O  1104L              // 48
#define DIS_O  1152L              // 50000 rsqrt(deg+1)
#define XS_O   51152L             // 500000 x' = dis*x (fp32)
#define FLOATS_TOT 551152L
// then: h' [NND*96] bf16, wct [96*96] bf16
// then ints: cnt[50000], start[50000], part[800000], smat[NW*PB], cmat[NW*PB];
// then csr u16 [NW*EW_CAP]

__device__ __forceinline__ float b2f(bf16 v) { return __bfloat162float(v); }
__device__ __forceinline__ float bfLo(unsigned int p) { return __uint_as_float(p << 16); }
__device__ __forceinline__ float bfHi(unsigned int p) { return __uint_as_float(p & 0xffff0000u); }
__device__ __forceinline__ unsigned short f2bu(float v) {
    return __bfloat16_as_ushort(__float2bfloat16(v));
}

// unpack-accumulate one 192B h'-row third-chunk triple into the 24-float acc
#define ACCADD(Q0, Q1, Q2) do {                                             \
    const uint4 q0 = (Q0), q1 = (Q1), q2 = (Q2);                            \
    acc[0][0] += bfLo(q0.x); acc[0][1] += bfHi(q0.x);                       \
    acc[0][2] += bfLo(q0.y); acc[0][3] += bfHi(q0.y);                       \
    acc[0][4] += bfLo(q0.z); acc[0][5] += bfHi(q0.z);                       \
    acc[0][6] += bfLo(q0.w); acc[0][7] += bfHi(q0.w);                       \
    acc[1][0] += bfLo(q1.x); acc[1][1] += bfHi(q1.x);                       \
    acc[1][2] += bfLo(q1.y); acc[1][3] += bfHi(q1.y);                       \
    acc[1][4] += bfLo(q1.z); acc[1][5] += bfHi(q1.z);                       \
    acc[1][6] += bfLo(q1.w); acc[1][7] += bfHi(q1.w);                       \
    acc[2][0] += bfLo(q2.x); acc[2][1] += bfHi(q2.x);                       \
    acc[2][2] += bfLo(q2.y); acc[2][3] += bfHi(q2.y);                       \
    acc[2][4] += bfLo(q2.z); acc[2][5] += bfHi(q2.z);                       \
    acc[2][6] += bfLo(q2.w); acc[2][7] += bfHi(q2.w);                       \
} while (0)

// LDS: one union reused across the 4 phases (max = phase D, 48 KB)
union SU {
    struct { int counts[NW]; int cur[NW]; unsigned int buf[PBE]; } a;           // 16.8 KB
    struct { int Lrun[PB]; int Srun[PB]; int hist[SPAN]; int cur[SPAN];
             float dl[SPAN]; int wsum[8]; } b;                                   // 7.8 KB
    struct { float w1s[1056]; } c;                                               // 4.2 KB
    struct { float4 red[8][64][6]; } d;                                          // 48 KB
};

// Single cooperative kernel: partition -> grid.sync -> window/CSR build ->
// grid.sync -> layer1 -> grid.sync -> gather+MFMA heads.
// REGISTER FIX (R4/R5 lesson): the backend's default heuristic targeted
// 8 waves/EU and allocated 64 VGPR, spilling ~350B/thread (=180MB HBM round
// trip, 330us). amdgpu_waves_per_eu(4,4) pins occupancy at exactly 4
// waves/EU (the 1024-thread block's natural occupancy) -> 128-VGPR budget.
// Phase D also de-unrolled 4->2 edges (identical accumulation order) to
// keep peak pressure ~75 regs.
__global__ __launch_bounds__(1024)
__attribute__((amdgpu_waves_per_eu(4, 4)))
void k_all(
        const int* ei, const void* x,
        const void* w1, const void* b1, const void* wm, const void* bm,
        const void* wl, const void* bl,
        float* F, unsigned short* wct, unsigned int* part, int* smat, int* cmat,
        int* cnt, int* start, unsigned short* csr, unsigned short* h, void* dout) {
    cg::grid_group grid = cg::this_grid();
    __shared__ SU u;
    __shared__ int s_oddnz, s_big;
    const int tid = threadIdx.x, bid = blockIdx.x;
    const int wave = tid >> 6, lane = tid & 63;

    // ---- dtype sniff (every block; ~5 KB L2-broadcast reads) ----
    if (tid == 0) { s_oddnz = 0; s_big = 0; }
    if (tid < NW) u.a.counts[tid] = 0;
    __syncthreads();
    if (tid < 128) {
        if (ei[2 * tid + 1] != 0) atomicOr(&s_oddnz, 1);
    }
    if (tid < 256) {
        const unsigned short* xs = (const unsigned short*)x;
        unsigned short uu = xs[tid * 8];
        float f = __uint_as_float(((unsigned int)uu) << 16);
        int big = !(fabsf(f) < 64.0f);
        unsigned short u2 = xs[tid * 8 + 5];
        float f2 = __uint_as_float(((unsigned int)u2) << 16);
        big |= !(fabsf(f2) < 64.0f);
        if (big) atomicOr(&s_big, 1);
    }
    __syncthreads();
    const int iw = (s_oddnz == 0) ? 1 : 0;   // 1 = int64 edge_index
    const int ff = s_big ? 1 : 0;            // 1 = fp32 floats

    // ======== Phase A: partition + weight conversion ========
    if (bid < 11) {   // weights: 11*1024 = 11264 >= 10368
        int idx = bid * 1024 + tid;
        if (idx < 10368) {
            const void* src; long off; int mode; long dst = 0;
            if      (idx < 960)  { src = w1; off = idx;        mode = 0; dst = W1F_O + idx; }
            else if (idx < 1056) { src = b1; off = idx - 960;  mode = 0; dst = B1F_O + (idx - 960); }
            else if (idx < 1104) { src = bm; off = idx - 1056; mode = 0; dst = BMF_O + (idx - 1056); }
            else if (idx < 1152) { src = bl; off = idx - 1104; mode = 0; dst = BLF_O + (idx - 1104); }
            else if (idx < 5760) { src = wm; off = idx - 1152; mode = 1; }
            else                 { src = wl; off = idx - 5760; mode = 2; }
            float v = ff ? ((const float*)src)[off] : b2f(((const bf16*)src)[off]);
            if (mode == 0) F[dst] = v;
            else if (mode == 1) wct[(off % OUTC) * (long)HID + off / OUTC] = f2bu(v);
            else                wct[(OUTC + off % OUTC) * (long)HID + off / OUTC] = f2bu(v);
        }
    }
    if (bid < PB) {
        unsigned int wreg[4];
        int base = bid * 1000;              // groups of 4 edges
        int j = tid;
        if (j < 1000) {
            int j4 = base + j;
            int r0, r1, r2, r3, c0, c1, c2, c3;
            if (iw) {
                const int4* pr = (const int4*)ei;
                const int4* pc = (const int4*)(ei + 2L * NED);
                int4 ra = pr[2 * j4], rb = pr[2 * j4 + 1];
                int4 ca = pc[2 * j4], cb = pc[2 * j4 + 1];
                r0 = ra.x; r1 = ra.z; r2 = rb.x; r3 = rb.z;
                c0 = ca.x; c1 = ca.z; c2 = cb.x; c3 = cb.z;
            } else {
                int4 ra = ((const int4*)ei)[j4];
                int4 ca = ((const int4*)(ei + NED))[j4];
                r0 = ra.x; r1 = ra.y; r2 = ra.z; r3 = ra.w;
                c0 = ca.x; c1 = ca.y; c2 = ca.z; c3 = ca.w;
            }
            wreg[0] = (unsigned)r0 | ((unsigned)c0 << 16);
            wreg[1] = (unsigned)r1 | ((unsigned)c1 << 16);
            wreg[2] = (unsigned)r2 | ((unsigned)c2 << 16);
            wreg[3] = (unsigned)r3 | ((unsigned)c3 << 16);
            atomicAdd(&u.a.counts[wreg[0] >> 25], 1);
            atomicAdd(&u.a.counts[wreg[1] >> 25], 1);
            atomicAdd(&u.a.counts[wreg[2] >> 25], 1);
            atomicAdd(&u.a.counts[wreg[3] >> 25], 1);
        }
        __syncthreads();
        if (tid < NW) {   // tiny serial exclusive scan per thread
            int run = 0;
            for (int jj = 0; jj < tid; ++jj) run += u.a.counts[jj];
            u.a.cur[tid] = run;
            cmat[tid * PB + bid] = u.a.counts[tid];
            smat[tid * PB + bid] = bid * PBE + run;
        }
        __syncthreads();
        if (j < 1000) {
#pragma unroll
            for (int q = 0; q < 4; ++q) {
                unsigned int w = wreg[q];
                int pos = atomicAdd(&u.a.cur[w >> 25], 1);
                u.a.buf[pos] = w;
            }
        }
        __syncthreads();
        for (int i = tid; i < PBE; i += 1024) part[bid * PBE + i] = u.a.buf[i];
    }
    __threadfence();
    grid.sync();

    // ======== Phase B: window build (blocks 0..97) ========
    if (bid < NW) {
        const int w = bid;
        if (tid < PB) { u.b.Lrun[tid] = cmat[w * PB + tid]; u.b.Srun[tid] = smat[w * PB + tid]; }
        if (tid < SPAN) u.b.hist[tid] = 0;
        __syncthreads();
        unsigned int lo = (unsigned)w * SPAN;
        for (int rb = wave; rb < PB; rb += 16) {
            int L = u.b.Lrun[rb], S = u.b.Srun[rb];
            for (int i = lane; i < L; i += 64)
                atomicAdd(&u.b.hist[(part[S + i] >> 16) - lo], 1);
        }
        __syncthreads();
        // inclusive scan: in-wave shuffle + 8-wide cross-wave
        int v = 0;
        if (tid < SPAN) {
            v = u.b.hist[tid];
#pragma unroll
            for (int d = 1; d < 64; d <<= 1) {
                int t = __shfl_up(v, d, 64);
                if (lane >= d) v += t;
            }
            if (lane == 63) u.b.wsum[wave] = v;
        }
        __syncthreads();
        if (tid < 8) {
            int sv = u.b.wsum[tid];
#pragma unroll
            for (int d = 1; d < 8; d <<= 1) {
                int t = __shfl_up(sv, d, 64);
                if (tid >= d) sv += t;
            }
            u.b.wsum[tid] = sv;
        }
        __syncthreads();
        if (tid < SPAN) {
            int stv = v + (wave ? u.b.wsum[wave - 1] : 0);
            int h0 = u.b.hist[tid];
            int abs0 = w * EW_CAP + (stv - h0);
            u.b.cur[tid] = abs0;
            float dis = rsqrtf((float)h0 + 1.0f);
            u.b.dl[tid] = dis;
            int g = (int)lo + tid;
            if (g < NND) {
                cnt[g] = h0; start[g] = abs0;
                F[DIS_O + g] = dis;
            }
        }
        __syncthreads();
        // x' = dis * x from raw input (coalesced)
        for (int i = tid; i < SPAN * INC; i += 1024) {
            int node = (int)lo + i / INC;
            if (node < NND) {
                long xo = (long)node * INC + (i % INC);
                float xv = ff ? ((const float*)x)[xo] : b2f(((const bf16*)x)[xo]);
                F[XS_O + xo] = u.b.dl[i / INC] * xv;
            }
        }
        int lim = (w + 1) * EW_CAP;
        for (int rb = wave; rb < PB; rb += 16) {
            int L = u.b.Lrun[rb], S = u.b.Srun[rb];
            for (int i = lane; i < L; i += 64) {
                unsigned int e = part[S + i];
                int pos = atomicAdd(&u.b.cur[(e >> 16) - lo], 1);
                if (pos < lim) csr[pos] = (unsigned short)(e & 0xffffu);
            }
        }
    }
    __threadfence();
    grid.sync();

    // ======== Phase C: layer1 (grid-stride, 8 threads/node) ========
    for (int i = tid; i < 1056; i += 1024) u.c.w1s[i] = F[W1F_O + i];
    __syncthreads();
    for (int idx = bid * 1024 + tid; idx < NND * 8; idx += GRID * 1024) {
        int node = idx >> 3, sub = idx & 7;
        int s = start[node], t = s + cnt[node];
        int lim = ((node >> 9) + 1) * EW_CAP;
        if (t > lim) t = lim;                 // capacity guard
        float ax[INC];
#pragma unroll
        for (int j = 0; j < INC; ++j) ax[j] = 0.0f;
        int k = s + sub;
        for (; k + 8 < t; k += 16) {          // 2 records: k and k+8
            int s0 = csr[k], s1 = csr[k + 8];
            const float2* x0 = (const float2*)(F + XS_O + (long)s0 * INC);
            const float2* x1 = (const float2*)(F + XS_O + (long)s1 * INC);
            float2 a0 = x0[0], a1 = x0[1], a2 = x0[2], a3 = x0[3], a4 = x0[4];
            float2 b0 = x1[0], b1 = x1[1], b2 = x1[2], b3 = x1[3], b4 = x1[4];
            ax[0] += a0.x + b0.x; ax[1] += a0.y + b0.y;
            ax[2] += a1.x + b1.x; ax[3] += a1.y + b1.y;
            ax[4] += a2.x + b2.x; ax[5] += a2.y + b2.y;
            ax[6] += a3.x + b3.x; ax[7] += a3.y + b3.y;
            ax[8] += a4.x + b4.x; ax[9] += a4.y + b4.y;
        }
        if (k < t) {                           // tail: at most one record
            int s0 = csr[k];
            const float2* x0 = (const float2*)(F + XS_O + (long)s0 * INC);
#pragma unroll
            for (int j = 0; j < 5; ++j) {
                float2 v = x0[j];
                ax[2 * j]     += v.x;
                ax[2 * j + 1] += v.y;
            }
        }
        if (sub == 0) {   // self term: + x'_c
            const float2* xr = (const float2*)(F + XS_O + (long)node * INC);
#pragma unroll
            for (int j = 0; j < 5; ++j) {
                float2 v = xr[j];
                ax[2 * j]     += v.x;
                ax[2 * j + 1] += v.y;
            }
        }
        // octet butterfly (whole octets active together; masks stay in-octet)
#pragma unroll
        for (int j = 0; j < INC; ++j) {
            ax[j] += __shfl_xor(ax[j], 1, 64);
            ax[j] += __shfl_xor(ax[j], 2, 64);
            ax[j] += __shfl_xor(ax[j], 4, 64);
        }
        float dn = F[DIS_O + node];
#pragma unroll
        for (int j = 0; j < INC; ++j) ax[j] *= dn;
        int f0 = sub * 12;
        unsigned int* hrow = (unsigned int*)(h + (size_t)node * HID);
#pragma unroll
        for (int f = f0; f < f0 + 12; f += 2) {
            float a0 = u.c.w1s[960 + f], a1 = u.c.w1s[960 + f + 1];
#pragma unroll
            for (int kk = 0; kk < INC; ++kk) {
                a0 = fmaf(ax[kk], u.c.w1s[kk * HID + f], a0);
                a1 = fmaf(ax[kk], u.c.w1s[kk * HID + f + 1], a1);
            }
            a0 = fmaxf(a0, 0.0f) * dn;     // h' = dis_c * relu(...)
            a1 = fmaxf(a1, 0.0f) * dn;
            unsigned int u0 = f2bu(a0), u1 = f2bu(a1);
            hrow[f >> 1] = u0 | (u1 << 16);
        }
    }
    __threadfence();
    grid.sync();

    // ======== Phase D: gather + MFMA heads ========
    // 16 waves = 8 tile-slots x 2 halves; tiles stride GRID*8 = 2048; 2 passes.
    {
        const int slot = wave >> 1, half = wave & 1;
        const int l16 = lane & 15, quad = lane >> 4;
        const uint4* hb4 = (const uint4*)h;   // h row = 12 uint4 (192 B)
#pragma unroll 1
        for (int p = 0; p < 2; ++p) {
            int mtile = p * (GRID * 8) + bid * 8 + slot;
            bool act = mtile < MTILES;
            int node = 0, s = 0, c = 0;
            float acc[3][8];
#pragma unroll
            for (int g = 0; g < 3; ++g)
#pragma unroll
                for (int j = 0; j < 8; ++j) acc[g][j] = 0.0f;
            if (act) {
                node = mtile * 16 + l16;
                long rowq = (long)node * 12;
                s = start[node]; c = cnt[node];
                int lim = ((node >> 9) + 1) * EW_CAP;
                if (s + c > lim) c = lim - s;
                if (half == 0) {   // self term
                    ACCADD(hb4[rowq + quad], hb4[rowq + 4 + quad], hb4[rowq + 8 + quad]);
                }
                int k = half;
                for (; k + 2 < c; k += 4) {   // 2 edges of this half in flight
                    int e0 = csr[s + k], e1 = csr[s + k + 2];
                    long r0 = (long)e0 * 12, r1 = (long)e1 * 12;
                    uint4 x00 = hb4[r0 + quad], x01 = hb4[r0 + 4 + quad], x02 = hb4[r0 + 8 + quad];
                    uint4 x10 = hb4[r1 + quad], x11 = hb4[r1 + 4 + quad], x12 = hb4[r1 + 8 + quad];
                    ACCADD(x00, x01, x02);
                    ACCADD(x10, x11, x12);
                }
                for (; k < c; k += 2) {
                    int e0 = csr[s + k];
                    long r0 = (long)e0 * 12;
                    ACCADD(hb4[r0 + quad], hb4[r0 + 4 + quad], hb4[r0 + 8 + quad]);
                }
            }
            if (act && half == 1) {
#pragma unroll
                for (int g = 0; g < 3; ++g) {
                    u.d.red[slot][lane][2 * g]     = make_float4(acc[g][0], acc[g][1], acc[g][2], acc[g][3]);
                    u.d.red[slot][lane][2 * g + 1] = make_float4(acc[g][4], acc[g][5], acc[g][6], acc[g][7]);
                }
            }
            __syncthreads();
            if (act && half == 0) {
#pragma unroll
                for (int g = 0; g < 3; ++g) {
                    float4 uu = u.d.red[slot][lane][2 * g], vv = u.d.red[slot][lane][2 * g + 1];
                    acc[g][0] += uu.x; acc[g][1] += uu.y; acc[g][2] += uu.z; acc[g][3] += uu.w;
                    acc[g][4] += vv.x; acc[g][5] += vv.y; acc[g][6] += vv.z; acc[g][7] += vv.w;
                }
                float dn = F[DIS_O + node];
                short8 af[3];
#pragma unroll
                for (int g = 0; g < 3; ++g)
#pragma unroll
                    for (int j = 0; j < 8; ++j)
                        af[g][j] = (short)f2bu(acc[g][j] * dn);
#pragma unroll
                for (int nt = 0; nt < 6; ++nt) {
                    const unsigned short* wb = wct + ((size_t)nt * 16 + l16) * HID + quad * 8;
                    short8 b0 = *(const short8*)(wb);
                    short8 b1 = *(const short8*)(wb + 32);
                    short8 b2 = *(const short8*)(wb + 64);
                    f32x4 cacc = {0.0f, 0.0f, 0.0f, 0.0f};
                    cacc = __builtin_amdgcn_mfma_f32_16x16x32_bf16(af[0], b0, cacc, 0, 0, 0);
                    cacc = __builtin_amdgcn_mfma_f32_16x16x32_bf16(af[1], b1, cacc, 0, 0, 0);
                    cacc = __builtin_amdgcn_mfma_f32_16x16x32_bf16(af[2], b2, cacc, 0, 0, 0);
                    int n = nt * 16 + l16;                 // 0..95: <48 mu, >=48 logstd
                    float bias = (n < OUTC) ? F[BMF_O + n] : F[BLF_O + n - OUTC];
                    long obase = (n < OUTC) ? ((long)n) : (NOUT + (long)(n - OUTC));
#pragma unroll
                    for (int r = 0; r < 4; ++r) {
                        int m = mtile * 16 + quad * 4 + r;
                        float val = cacc[r] + bias;
                        long oi = (long)m * OUTC + obase;
                        if (ff) ((float*)dout)[oi] = val;
                        else    ((bf16*)dout)[oi] = __float2bfloat16(val);
                    }
                }
            }
            __syncthreads();   // red reuse safety for next pass
        }
    }
}

extern "C" void kernel_launch(void* const* d_in, const int* in_sizes, int n_in,
                              void* d_out, int out_size, void* d_ws, size_t ws_size,
                              hipStream_t stream) {
    const int* ei = (const int*)d_in[1];
    const void* x = d_in[0];
    const void* w1 = d_in[2]; const void* b1 = d_in[3];
    const void* wm = d_in[4]; const void* bm = d_in[5];
    const void* wl = d_in[6]; const void* bl = d_in[7];
    float* F = (float*)((char*)d_ws + 256);
    unsigned short* h   = (unsigned short*)(F + FLOATS_TOT);
    unsigned short* wct = h + (size_t)NND * HID;
    int* cnt   = (int*)(wct + (size_t)HID * HID);
    int* start = cnt + NND;
    unsigned int* part = (unsigned int*)(start + NND);
    int* smat = (int*)(part + NED);
    int* cmat = smat + NW * PB;
    unsigned short* csr = (unsigned short*)(cmat + NW * PB);

    void* args[] = {
        (void*)&ei, (void*)&x, (void*)&w1, (void*)&b1, (void*)&wm, (void*)&bm,
        (void*)&wl, (void*)&bl, (void*)&F, (void*)&wct, (void*)&part,
        (void*)&smat, (void*)&cmat, (void*)&cnt, (void*)&start, (void*)&csr,
        (void*)&h, (void*)&d_out
    };
    hipLaunchCooperativeKernel((void*)k_all, dim3(GRID), dim3(1024), args, 0, stream);
}

// Round 8
// 143.551 us; speedup vs baseline: 4.2118x; 4.1059x over previous
//
#include <hip/hip_runtime.h>
#include <hip/hip_bf16.h>

// Problem constants
#define NND 50000      // nodes
#define NED 800000     // edges (without self-loops)
#define INC 10
#define HID 96
#define OUTC 48
#define NOUT (NND*OUTC)
#define MTILES 3125    // 50000 / 16
#define NW 98          // dest windows of SPAN nodes
#define SPAN 512
#define EW_CAP 9216    // CSR capacity per window (Poisson 8163 + 11 sigma)
#define PB 200         // partition blocks
#define PBE 4000       // edges per partition block (200*4000 = 800000 exact)

typedef __hip_bfloat16 bf16;
typedef __attribute__((ext_vector_type(8))) short short8;
typedef __attribute__((ext_vector_type(4))) float f32x4;
typedef __attribute__((ext_vector_type(4))) int iv4;   // NT-loadable 16B int vector

// ---- workspace layout ----
// header ints: [0..1] flags (k_part block 0). 256B reserved.
// F floats (from d_ws+256):
#define W1F_O  0L                 // 960 (W1 then b1: 1056 contiguous)
#define B1F_O  960L               // 96
#define BMF_O  1056L              // 48
#define BLF_O  1104L              // 48
#define DIS_O  1152L              // 50000 rsqrt(deg+1)   (k_win)
#define XS_O   51152L             // 500000 x' = dis*x    (k_win, fp32)
#define FLOATS_TOT 551152L
// then: h' [NND*96] bf16 (dis-prescaled hidden), wct [96*96] bf16
// then ints: cnt[50000], start[50000], part[800000], smat[NW*PB], cmat[NW*PB];
// then csr u16 [NW*EW_CAP]

__device__ __forceinline__ float b2f(bf16 v) { return __bfloat162float(v); }
__device__ __forceinline__ float bfLo(unsigned int p) { return __uint_as_float(p << 16); }
__device__ __forceinline__ float bfHi(unsigned int p) { return __uint_as_float(p & 0xffff0000u); }
__device__ __forceinline__ unsigned short f2bu(float v) {
    return __bfloat16_as_ushort(__float2bfloat16(v));
}

// unpack-accumulate one 192B h'-row third-chunk triple into the 24-float acc
#define ACCADD(Q0, Q1, Q2) do {                                             \
    const uint4 q0 = (Q0), q1 = (Q1), q2 = (Q2);                            \
    acc[0][0] += bfLo(q0.x); acc[0][1] += bfHi(q0.x);                       \
    acc[0][2] += bfLo(q0.y); acc[0][3] += bfHi(q0.y);                       \
    acc[0][4] += bfLo(q0.z); acc[0][5] += bfHi(q0.z);                       \
    acc[0][6] += bfLo(q0.w); acc[0][7] += bfHi(q0.w);                       \
    acc[1][0] += bfLo(q1.x); acc[1][1] += bfHi(q1.x);                       \
    acc[1][2] += bfLo(q1.y); acc[1][3] += bfHi(q1.y);                       \
    acc[1][4] += bfLo(q1.z); acc[1][5] += bfHi(q1.z);                       \
    acc[1][6] += bfLo(q1.w); acc[1][7] += bfHi(q1.w);                       \
    acc[2][0] += bfLo(q2.x); acc[2][1] += bfHi(q2.x);                       \
    acc[2][2] += bfLo(q2.y); acc[2][3] += bfHi(q2.y);                       \
    acc[2][4] += bfLo(q2.z); acc[2][5] += bfHi(q2.z);                       \
    acc[2][6] += bfLo(q2.w); acc[2][7] += bfHi(q2.w);                       \
} while (0)

// K1: partition + weights. Block b owns edges [b*4000,+4000): block-local sniff,
// read edge slice ONCE (non-temporal via ext_vector iv4: single-pass stream,
// don't pollute L2), LDS histogram by dest window (c>>9), LDS scan, LDS place,
// coalesced 16 KB run write + run matrix. Blocks 0..10 convert the weights.
__global__ __launch_bounds__(1024) void k_part(const int* ei, const void* x,
                                               const void* w1, const void* b1,
                                               const void* wm, const void* bm,
                                               const void* wl, const void* bl,
                                               int* flags, float* F, unsigned short* wct,
                                               unsigned int* part, int* smat, int* cmat) {
    __shared__ int s_oddnz, s_big;
    __shared__ int counts[NW], cur[NW];
    __shared__ unsigned int buf[PBE];
    int tid = threadIdx.x;
    if (tid == 0) { s_oddnz = 0; s_big = 0; }
    if (tid < NW) counts[tid] = 0;
    __syncthreads();
    {   // dtype sniff (block-local; ~5 KB L2-broadcast reads)
        if (tid < 128) {
            if (ei[2 * tid + 1] != 0) atomicOr(&s_oddnz, 1);
        }
        if (tid < 256) {
            const unsigned short* xs = (const unsigned short*)x;
            unsigned short u = xs[tid * 8];
            float f = __uint_as_float(((unsigned int)u) << 16);
            int big = !(fabsf(f) < 64.0f);
            unsigned short u2 = xs[tid * 8 + 5];
            float f2 = __uint_as_float(((unsigned int)u2) << 16);
            big |= !(fabsf(f2) < 64.0f);
            if (big) atomicOr(&s_big, 1);
        }
    }
    __syncthreads();
    int iw = (s_oddnz == 0) ? 1 : 0;   // 1 = int64 edge_index
    int ff = s_big ? 1 : 0;            // 1 = fp32 floats
    if (blockIdx.x == 0 && tid == 0) { flags[0] = iw; flags[1] = ff; }

    // weight conversion (blocks 0..10; 11*1024 = 11264 >= 10368)
    if (blockIdx.x < 11) {
        int idx = blockIdx.x * 1024 + tid;
        if (idx < 10368) {
            const void* src; long off; int mode; long dst = 0;
            if      (idx < 960)  { src = w1; off = idx;        mode = 0; dst = W1F_O + idx; }
            else if (idx < 1056) { src = b1; off = idx - 960;  mode = 0; dst = B1F_O + (idx - 960); }
            else if (idx < 1104) { src = bm; off = idx - 1056; mode = 0; dst = BMF_O + (idx - 1056); }
            else if (idx < 1152) { src = bl; off = idx - 1104; mode = 0; dst = BLF_O + (idx - 1104); }
            else if (idx < 5760) { src = wm; off = idx - 1152; mode = 1; }
            else                 { src = wl; off = idx - 5760; mode = 2; }
            float v = ff ? ((const float*)src)[off] : b2f(((const bf16*)src)[off]);
            if (mode == 0) F[dst] = v;
            else if (mode == 1) wct[(off % OUTC) * (long)HID + off / OUTC] = f2bu(v);
            else                wct[(OUTC + off % OUTC) * (long)HID + off / OUTC] = f2bu(v);
        }
    }

    // read own edge slice once -> regs (packed row | col<<16); 1 group of 4/thread
    unsigned int wreg[4];
    int base = blockIdx.x * 1000;              // groups of 4 edges
    int j = tid;
    if (j < 1000) {
        int j4 = base + j;
        int r0, r1, r2, r3, c0, c1, c2, c3;
        if (iw) {
            const iv4* pr = (const iv4*)ei;
            const iv4* pc = (const iv4*)(ei + 2L * NED);
            iv4 ra = __builtin_nontemporal_load(&pr[2 * j4]);
            iv4 rb = __builtin_nontemporal_load(&pr[2 * j4 + 1]);
            iv4 ca = __builtin_nontemporal_load(&pc[2 * j4]);
            iv4 cb = __builtin_nontemporal_load(&pc[2 * j4 + 1]);
            r0 = ra[0]; r1 = ra[2]; r2 = rb[0]; r3 = rb[2];
            c0 = ca[0]; c1 = ca[2]; c2 = cb[0]; c3 = cb[2];
        } else {
            iv4 ra = __builtin_nontemporal_load(&((const iv4*)ei)[j4]);
            iv4 ca = __builtin_nontemporal_load(&((const iv4*)(ei + NED))[j4]);
            r0 = ra[0]; r1 = ra[1]; r2 = ra[2]; r3 = ra[3];
            c0 = ca[0]; c1 = ca[1]; c2 = ca[2]; c3 = ca[3];
        }
        wreg[0] = (unsigned)r0 | ((unsigned)c0 << 16);
        wreg[1] = (unsigned)r1 | ((unsigned)c1 << 16);
        wreg[2] = (unsigned)r2 | ((unsigned)c2 << 16);
        wreg[3] = (unsigned)r3 | ((unsigned)c3 << 16);
        atomicAdd(&counts[wreg[0] >> 25], 1);
        atomicAdd(&counts[wreg[1] >> 25], 1);
        atomicAdd(&counts[wreg[2] >> 25], 1);
        atomicAdd(&counts[wreg[3] >> 25], 1);
    }
    __syncthreads();
    if (tid < NW) {   // tiny serial exclusive scan per thread
        int run = 0;
        for (int jj = 0; jj < tid; ++jj) run += counts[jj];
        cur[tid] = run;
        cmat[tid * PB + blockIdx.x] = counts[tid];
        smat[tid * PB + blockIdx.x] = blockIdx.x * PBE + run;
    }
    __syncthreads();
    if (j < 1000) {
#pragma unroll
        for (int q = 0; q < 4; ++q) {
            unsigned int w = wreg[q];
            int pos = atomicAdd(&cur[w >> 25], 1);
            buf[pos] = w;
        }
    }
    __syncthreads();
    for (int i = tid; i < PBE; i += 1024) part[blockIdx.x * PBE + i] = buf[i];
}

// K2: window build. Block w reads only its ~200 runs (~33 KB, L2-hot):
// LDS histogram (512 nodes) -> wave-shuffle scan (2 barriers) ->
// cnt/start/dis writes + x' = dis*x from RAW input x -> LDS-cursor place of
// u16 src records into the window's PRIVATE 18 KB CSR segment. 16 waves.
__global__ __launch_bounds__(1024) void k_win(const unsigned int* part, const int* smat,
                                              const int* cmat, const void* x, float* F,
                                              int* cnt, int* start, unsigned short* csr) {
    __shared__ int Lrun[PB], Srun[PB];
    __shared__ int hist[SPAN], cur[SPAN];
    __shared__ float dl[SPAN];
    __shared__ int wsum[8];
    __shared__ int s_big;
    int tid = threadIdx.x;
    int w = blockIdx.x;
    if (tid == 0) s_big = 0;
    if (tid < PB) { Lrun[tid] = cmat[w * PB + tid]; Srun[tid] = smat[w * PB + tid]; }
    if (tid < SPAN) hist[tid] = 0;
    __syncthreads();
    if (tid < 256) {   // ff sniff
        const unsigned short* xs = (const unsigned short*)x;
        unsigned short u = xs[tid * 8];
        float f = __uint_as_float(((unsigned int)u) << 16);
        int big = !(fabsf(f) < 64.0f);
        unsigned short u2 = xs[tid * 8 + 5];
        float f2 = __uint_as_float(((unsigned int)u2) << 16);
        big |= !(fabsf(f2) < 64.0f);
        if (big) atomicOr(&s_big, 1);
    }
    unsigned int lo = (unsigned)w * SPAN;
    int wave = tid >> 6, lane = tid & 63;
    for (int rb = wave; rb < PB; rb += 16) {
        int L = Lrun[rb], S = Srun[rb];
        for (int i = lane; i < L; i += 64)
            atomicAdd(&hist[(part[S + i] >> 16) - lo], 1);
    }
    __syncthreads();
    int ff = s_big;
    // inclusive scan of hist[0..511]: in-wave shuffle scan + 8-wide cross-wave
    int v = 0;
    if (tid < SPAN) {
        v = hist[tid];
#pragma unroll
        for (int d = 1; d < 64; d <<= 1) {
            int t = __shfl_up(v, d, 64);
            if (lane >= d) v += t;
        }
        if (lane == 63) wsum[wave] = v;
    }
    __syncthreads();
    if (tid < 8) {
        int sv = wsum[tid];
#pragma unroll
        for (int d = 1; d < 8; d <<= 1) {
            int t = __shfl_up(sv, d, 64);
            if (tid >= d) sv += t;
        }
        wsum[tid] = sv;   // inclusive cross-wave sums
    }
    __syncthreads();
    if (tid < SPAN) {
        int stv = v + (wave ? wsum[wave - 1] : 0);   // inclusive scan value
        int h0 = hist[tid];
        int abs0 = w * EW_CAP + (stv - h0);
        cur[tid] = abs0;
        float dis = rsqrtf((float)h0 + 1.0f);
        dl[tid] = dis;
        int g = (int)lo + tid;
        if (g < NND) {
            cnt[g] = h0; start[g] = abs0;
            F[DIS_O + g] = dis;
        }
    }
    __syncthreads();
    // x' = dis * x from raw input (coalesced)
    for (int i = tid; i < SPAN * INC; i += 1024) {
        int node = (int)lo + i / INC;
        if (node < NND) {
            long xo = (long)node * INC + (i % INC);
            float xv = ff ? ((const float*)x)[xo] : b2f(((const bf16*)x)[xo]);
            F[XS_O + xo] = dl[i / INC] * xv;
        }
    }
    int lim = (w + 1) * EW_CAP;
    for (int rb = wave; rb < PB; rb += 16) {
        int L = Lrun[rb], S = Srun[rb];
        for (int i = lane; i < L; i += 64) {
            unsigned int e = part[S + i];
            int pos = atomicAdd(&cur[(e >> 16) - lo], 1);
            if (pos < lim) csr[pos] = (unsigned short)(e & 0xffffu);
        }
    }
}

// K3: fused layer1 — EIGHT threads per node (octet in-wave), u16 records,
// 2-record-unrolled x' gather (10 independent row loads in flight), 3-step
// butterfly, scale by dis_c, 12-feature GEMV slice via LDS W1,
// write h' = dis_c * relu(...) as packed bf16. 6252 waves.
__global__ __launch_bounds__(256) void k_layer1(const int* cnt, const int* start,
                                                const unsigned short* csr, const float* F,
                                                unsigned short* h) {
    __shared__ float w1s[1056];   // W1 (960) then b1 (96), contiguous in F
    for (int i = threadIdx.x; i < 1056; i += 256) w1s[i] = F[W1F_O + i];
    __syncthreads();
    int idx = blockIdx.x * 256 + threadIdx.x;
    if (idx >= NND * 8) return;
    int node = idx >> 3, sub = idx & 7;
    int s = start[node], t = s + cnt[node];
    int lim = ((node >> 9) + 1) * EW_CAP;
    if (t > lim) t = lim;                 // capacity guard
    float ax[INC];
#pragma unroll
    for (int j = 0; j < INC; ++j) ax[j] = 0.0f;
    int k = s + sub;
    for (; k + 8 < t; k += 16) {          // 2 records: k and k+8
        int s0 = csr[k], s1 = csr[k + 8];
        const float2* x0 = (const float2*)(F + XS_O + (long)s0 * INC);
        const float2* x1 = (const float2*)(F + XS_O + (long)s1 * INC);
        float2 a0 = x0[0], a1 = x0[1], a2 = x0[2], a3 = x0[3], a4 = x0[4];
        float2 b0 = x1[0], b1 = x1[1], b2 = x1[2], b3 = x1[3], b4 = x1[4];
        ax[0] += a0.x + b0.x; ax[1] += a0.y + b0.y;
        ax[2] += a1.x + b1.x; ax[3] += a1.y + b1.y;
        ax[4] += a2.x + b2.x; ax[5] += a2.y + b2.y;
        ax[6] += a3.x + b3.x; ax[7] += a3.y + b3.y;
        ax[8] += a4.x + b4.x; ax[9] += a4.y + b4.y;
    }
    if (k < t) {                           // tail: at most one record
        int s0 = csr[k];
        const float2* x0 = (const float2*)(F + XS_O + (long)s0 * INC);
#pragma unroll
        for (int j = 0; j < 5; ++j) {
            float2 v = x0[j];
            ax[2 * j]     += v.x;
            ax[2 * j + 1] += v.y;
        }
    }
    if (sub == 0) {   // self term: + x'_c
        const float2* xr = (const float2*)(F + XS_O + (long)node * INC);
#pragma unroll
        for (int j = 0; j < 5; ++j) {
            float2 v = xr[j];
            ax[2 * j]     += v.x;
            ax[2 * j + 1] += v.y;
        }
    }
    // octet butterfly (octets are wave-aligned: masks 1,2,4 stay inside)
#pragma unroll
    for (int j = 0; j < INC; ++j) {
        ax[j] += __shfl_xor(ax[j], 1, 64);
        ax[j] += __shfl_xor(ax[j], 2, 64);
        ax[j] += __shfl_xor(ax[j], 4, 64);
    }
    float dn = F[DIS_O + node];
#pragma unroll
    for (int j = 0; j < INC; ++j) ax[j] *= dn;   // agg = dis_c * (sum + self)
    int f0 = sub * 12;
    unsigned int* hrow = (unsigned int*)(h + (size_t)node * HID);
#pragma unroll
    for (int f = f0; f < f0 + 12; f += 2) {
        float a0 = w1s[960 + f], a1 = w1s[960 + f + 1];
#pragma unroll
        for (int kk = 0; kk < INC; ++kk) {
            a0 = fmaf(ax[kk], w1s[kk * HID + f], a0);
            a1 = fmaf(ax[kk], w1s[kk * HID + f + 1], a1);
        }
        a0 = fmaxf(a0, 0.0f) * dn;     // h' = dis_c * relu(...)
        a1 = fmaxf(a1, 0.0f) * dn;
        unsigned int u0 = f2bu(a0), u1 = f2bu(a1);
        hrow[f >> 1] = u0 | (u1 << 16);
    }
}

// K4: fused gather + MFMA heads. TWO waves per 16-node M-tile (even/odd edges,
// 6 KB LDS pair-reduction), 4-edge unroll (12 independent uint4 loads in
// flight). Lane (l16,quad) accumulates feats in A-fragment layout (24 fp32);
// per edge the 4 quads read the 192B h'-row as 3 disjoint 64B uint4 chunks.
// Wave 0 then packs bf16 v-frags -> 18 MFMA -> bias -> store (non-temporal:
// streaming output must not evict L2-resident h' rows mid-gather). 6250 waves.
__global__ __launch_bounds__(128) void k_gh(const int* cnt, const int* start,
                                            const unsigned short* csr, const float* F,
                                            const unsigned short* h, const unsigned short* wct,
                                            const int* flags, void* dout) {
    __shared__ float4 red[64][6];
    int half = threadIdx.x >> 6;          // 0 or 1
    int lane = threadIdx.x & 63;
    int mtile = blockIdx.x;
    int l16 = lane & 15, quad = lane >> 4;
    int node = mtile * 16 + l16;

    const uint4* hb4 = (const uint4*)h;   // h row = 12 uint4 (192 B, 64B-aligned)
    long rowq = (long)node * 12;

    int s = start[node], c = cnt[node];
    int lim = ((node >> 9) + 1) * EW_CAP;
    if (s + c > lim) c = lim - s;

    float acc[3][8];
#pragma unroll
    for (int g = 0; g < 3; ++g)
#pragma unroll
        for (int j = 0; j < 8; ++j) acc[g][j] = 0.0f;
    if (half == 0) {   // self term: + h'_node
        ACCADD(hb4[rowq + quad], hb4[rowq + 4 + quad], hb4[rowq + 8 + quad]);
    }
    // edge loop: this half takes k = half, half+2, ... ; 4-edge unroll
    int k = half;
    for (; k + 6 < c; k += 8) {
        int e0 = csr[s + k], e1 = csr[s + k + 2], e2 = csr[s + k + 4], e3 = csr[s + k + 6];
        long r0 = (long)e0 * 12, r1 = (long)e1 * 12, r2 = (long)e2 * 12, r3 = (long)e3 * 12;
        uint4 x00 = hb4[r0 + quad], x01 = hb4[r0 + 4 + quad], x02 = hb4[r0 + 8 + quad];
        uint4 x10 = hb4[r1 + quad], x11 = hb4[r1 + 4 + quad], x12 = hb4[r1 + 8 + quad];
        uint4 x20 = hb4[r2 + quad], x21 = hb4[r2 + 4 + quad], x22 = hb4[r2 + 8 + quad];
        uint4 x30 = hb4[r3 + quad], x31 = hb4[r3 + 4 + quad], x32 = hb4[r3 + 8 + quad];
        ACCADD(x00, x01, x02);
        ACCADD(x10, x11, x12);
        ACCADD(x20, x21, x22);
        ACCADD(x30, x31, x32);
    }
    for (; k < c; k += 2) {   // tail: up to 3 single edges
        int e0 = csr[s + k];
        long r0 = (long)e0 * 12;
        ACCADD(hb4[r0 + quad], hb4[r0 + 4 + quad], hb4[r0 + 8 + quad]);
    }
    // pair reduction: half 1 -> LDS, half 0 adds
    if (half == 1) {
#pragma unroll
        for (int g = 0; g < 3; ++g) {
            red[lane][2 * g]     = make_float4(acc[g][0], acc[g][1], acc[g][2], acc[g][3]);
            red[lane][2 * g + 1] = make_float4(acc[g][4], acc[g][5], acc[g][6], acc[g][7]);
        }
    }
    __syncthreads();
    if (half == 1) return;
#pragma unroll
    for (int g = 0; g < 3; ++g) {
        float4 u = red[lane][2 * g], v = red[lane][2 * g + 1];
        acc[g][0] += u.x; acc[g][1] += u.y; acc[g][2] += u.z; acc[g][3] += u.w;
        acc[g][4] += v.x; acc[g][5] += v.y; acc[g][6] += v.z; acc[g][7] += v.w;
    }
    // v = dis_c * (...)  -> bf16 A-frags (identical rounding to before)
    float dn = F[DIS_O + node];
    short8 af[3];
#pragma unroll
    for (int g = 0; g < 3; ++g)
#pragma unroll
        for (int j = 0; j < 8; ++j)
            af[g][j] = (short)f2bu(acc[g][j] * dn);

    int ff = flags[1];
#pragma unroll
    for (int nt = 0; nt < 6; ++nt) {
        const unsigned short* wb = wct + ((size_t)nt * 16 + l16) * HID + quad * 8;
        short8 b0 = *(const short8*)(wb);
        short8 b1 = *(const short8*)(wb + 32);
        short8 b2 = *(const short8*)(wb + 64);
        f32x4 cacc = {0.0f, 0.0f, 0.0f, 0.0f};
        cacc = __builtin_amdgcn_mfma_f32_16x16x32_bf16(af[0], b0, cacc, 0, 0, 0);
        cacc = __builtin_amdgcn_mfma_f32_16x16x32_bf16(af[1], b1, cacc, 0, 0, 0);
        cacc = __builtin_amdgcn_mfma_f32_16x16x32_bf16(af[2], b2, cacc, 0, 0, 0);
        int n = nt * 16 + l16;                 // 0..95: <48 mu, >=48 logstd
        float bias = (n < OUTC) ? F[BMF_O + n] : F[BLF_O + n - OUTC];
        long obase = (n < OUTC) ? ((long)n) : (NOUT + (long)(n - OUTC));
#pragma unroll
        for (int r = 0; r < 4; ++r) {
            int m = mtile * 16 + quad * 4 + r;
            float val = cacc[r] + bias;
            long oi = (long)m * OUTC + obase;
            if (ff) __builtin_nontemporal_store(val, &((float*)dout)[oi]);
            else {
                unsigned short hv = f2bu(val);
                __builtin_nontemporal_store(hv, &((unsigned short*)dout)[oi]);
            }
        }
    }
}

extern "C" void kernel_launch(void* const* d_in, const int* in_sizes, int n_in,
                              void* d_out, int out_size, void* d_ws, size_t ws_size,
                              hipStream_t stream) {
    const int* ei = (const int*)d_in[1];
    int* flags = (int*)d_ws;
    float* F = (float*)((char*)d_ws + 256);
    unsigned short* h   = (unsigned short*)(F + FLOATS_TOT);
    unsigned short* wct = h + (size_t)NND * HID;
    int* cnt   = (int*)(wct + (size_t)HID * HID);
    int* start = cnt + NND;
    unsigned int* part = (unsigned int*)(start + NND);
    int* smat = (int*)(part + NED);
    int* cmat = smat + NW * PB;
    unsigned short* csr = (unsigned short*)(cmat + NW * PB);

    k_part<<<PB, 1024, 0, stream>>>(ei, d_in[0], d_in[2], d_in[3], d_in[4],
                                    d_in[5], d_in[6], d_in[7], flags, F, wct,
                                    part, smat, cmat);
    k_win<<<NW, 1024, 0, stream>>>(part, smat, cmat, d_in[0], F, cnt, start, csr);
    k_layer1<<<(NND * 8 + 255) / 256, 256, 0, stream>>>(cnt, start, csr, F, h);
    k_gh<<<MTILES, 128, 0, stream>>>(cnt, start, csr, F, h, wct, flags, d_out);
}